// Round 1
// baseline (1771.006 us; speedup 1.0000x reference)
//
#include <hip/hip_runtime.h>
#include <math.h>

#define L 2048
#define DM 1024
#define HD 64
#define NH 16
#define BATCH 2
#define TOPU 40
#define SCALE 0.125f
#define NEG_INF (-1e30f)

// ---------------------------------------------------------------------------
// Projection GEMM (NT): Y[b,h,l,d] = sum_k X[b*L+l,k] * W[h*64+d,k] + bias[h*64+d]
// 64x64 tile, BK=16, 256 threads, 4x4 per thread.
// ---------------------------------------------------------------------------
__global__ __launch_bounds__(256) void proj_kernel(const float* __restrict__ X,
    const float* __restrict__ W, const float* __restrict__ bias, float* __restrict__ Y)
{
    __shared__ float Xs[64][17];
    __shared__ float Ws[64][17];
    const int i0 = blockIdx.y * 64;
    const int j0 = blockIdx.x * 64;
    const int tid = threadIdx.x;
    const int tr = tid >> 4, tc = tid & 15;
    float acc[4][4] = {};
    for (int k0 = 0; k0 < DM; k0 += 16) {
#pragma unroll
        for (int q = 0; q < 4; q++) {
            int e = tid + 256 * q;
            int r = e >> 4, c = e & 15;
            Xs[r][c] = X[(size_t)(i0 + r) * DM + k0 + c];
            Ws[r][c] = W[(size_t)(j0 + r) * DM + k0 + c];
        }
        __syncthreads();
#pragma unroll
        for (int kk = 0; kk < 16; kk++) {
            float xr[4], wr[4];
#pragma unroll
            for (int r = 0; r < 4; r++) xr[r] = Xs[tr * 4 + r][kk];
#pragma unroll
            for (int c = 0; c < 4; c++) wr[c] = Ws[tc * 4 + c][kk];
#pragma unroll
            for (int r = 0; r < 4; r++)
#pragma unroll
                for (int c = 0; c < 4; c++) acc[r][c] += xr[r] * wr[c];
        }
        __syncthreads();
    }
#pragma unroll
    for (int r = 0; r < 4; r++) {
        int i = i0 + tr * 4 + r;
        int b = i >> 11, l = i & (L - 1);
#pragma unroll
        for (int c = 0; c < 4; c++) {
            int j = j0 + tc * 4 + c;
            int h = j >> 6, dd = j & 63;
            Y[(((size_t)(b * NH + h)) * L + l) * HD + dd] = acc[r][c] + bias[j];
        }
    }
}

// ---------------------------------------------------------------------------
// Sparsity: per (b,h), for each query q: scale*max_k(q.k) - scale*sum_k(q.k)/L
// Full 2048x2048 scores per head, never materialized. 64q x 64k tiles, 4x4/thread.
// ---------------------------------------------------------------------------
__global__ __launch_bounds__(256) void sparsity_kernel(const float* __restrict__ qh,
    const float* __restrict__ kh, float* __restrict__ sp)
{
    const int bh = blockIdx.x;
    const int q0 = blockIdx.y * 64;
    const float* Q = qh + (size_t)bh * L * HD;
    const float* K = kh + (size_t)bh * L * HD;
    __shared__ float Qs[64][65];
    __shared__ float Ks[64][65];
    const int tid = threadIdx.x;
    const int tr = tid >> 4, tc = tid & 15;
#pragma unroll
    for (int q = 0; q < 16; q++) {
        int e = tid + 256 * q;
        int r = e >> 6, c = e & 63;
        Qs[r][c] = Q[(size_t)(q0 + r) * HD + c];
    }
    float vmax[4] = {NEG_INF, NEG_INF, NEG_INF, NEG_INF};
    float vsum[4] = {0, 0, 0, 0};
    for (int k0 = 0; k0 < L; k0 += 64) {
#pragma unroll
        for (int q = 0; q < 16; q++) {
            int e = tid + 256 * q;
            int r = e >> 6, c = e & 63;
            Ks[r][c] = K[(size_t)(k0 + r) * HD + c];
        }
        __syncthreads();
        float s[4][4] = {};
        for (int d = 0; d < HD; d++) {
            float xr[4], wr[4];
#pragma unroll
            for (int r = 0; r < 4; r++) xr[r] = Qs[tr * 4 + r][d];
#pragma unroll
            for (int c = 0; c < 4; c++) wr[c] = Ks[tc * 4 + c][d];
#pragma unroll
            for (int r = 0; r < 4; r++)
#pragma unroll
                for (int c = 0; c < 4; c++) s[r][c] += xr[r] * wr[c];
        }
#pragma unroll
        for (int r = 0; r < 4; r++)
#pragma unroll
            for (int c = 0; c < 4; c++) {
                vmax[r] = fmaxf(vmax[r], s[r][c]);
                vsum[r] += s[r][c];
            }
        __syncthreads();
    }
#pragma unroll
    for (int off = 1; off < 16; off <<= 1) {
#pragma unroll
        for (int r = 0; r < 4; r++) {
            vmax[r] = fmaxf(vmax[r], __shfl_xor(vmax[r], off));
            vsum[r] += __shfl_xor(vsum[r], off);
        }
    }
    if (tc == 0) {
#pragma unroll
        for (int r = 0; r < 4; r++)
            sp[(size_t)bh * L + q0 + tr * 4 + r] =
                SCALE * vmax[r] - SCALE * vsum[r] * (1.0f / (float)L);
    }
}

// ---------------------------------------------------------------------------
// base[b,h,d] = mean_l vh[b,h,l,d]
// ---------------------------------------------------------------------------
__global__ __launch_bounds__(256) void base_kernel(const float* __restrict__ vh,
                                                   float* __restrict__ base)
{
    const int bh = blockIdx.x;
    const int tid = threadIdx.x;
    const int d = tid & 63, lg = tid >> 6;
    const float* V = vh + (size_t)bh * L * HD;
    float s = 0;
    for (int l = lg; l < L; l += 4) s += V[(size_t)l * HD + d];
    __shared__ float red[256];
    red[tid] = s;
    __syncthreads();
    if (tid < 64)
        base[bh * HD + d] = (red[d] + red[64 + d] + red[128 + d] + red[192 + d]) * (1.0f / (float)L);
}

// ---------------------------------------------------------------------------
// top-40 indices of sparsity per (b,h). Iterative argmax, tie -> lower index.
// ---------------------------------------------------------------------------
__global__ __launch_bounds__(256) void topk_kernel(const float* __restrict__ sp,
                                                   int* __restrict__ topk)
{
    const int bh = blockIdx.x;
    __shared__ float vals[L];
    __shared__ float rv[256];
    __shared__ int ri[256];
    const int tid = threadIdx.x;
    for (int i = 0; i < L / 256; i++) vals[tid + 256 * i] = sp[(size_t)bh * L + tid + 256 * i];
    __syncthreads();
    for (int it = 0; it < TOPU; it++) {
        float bv = NEG_INF;
        int bi = L;
        for (int i = 0; i < L / 256; i++) {
            int idx = tid + 256 * i;
            float v = vals[idx];
            if (v > bv || (v == bv && idx < bi)) { bv = v; bi = idx; }
        }
        rv[tid] = bv; ri[tid] = bi;
        __syncthreads();
        for (int s = 128; s > 0; s >>= 1) {
            if (tid < s) {
                if (rv[tid + s] > rv[tid] ||
                    (rv[tid + s] == rv[tid] && ri[tid + s] < ri[tid])) {
                    rv[tid] = rv[tid + s]; ri[tid] = ri[tid + s];
                }
            }
            __syncthreads();
        }
        if (tid == 0) { topk[bh * TOPU + it] = ri[0]; vals[ri[0]] = NEG_INF; }
        __syncthreads();
    }
}

// ---------------------------------------------------------------------------
// Full softmax attention for the 40 selected queries per (b,h); writes
// dctx = ctx - base (the correction applied on top of the broadcast base).
// Flash-style online softmax, 4 waves x 10 queries, lane = key (scores) / d (acc).
// ---------------------------------------------------------------------------
__global__ __launch_bounds__(256) void attn_top_kernel(const float* __restrict__ qh,
    const float* __restrict__ kh, const float* __restrict__ vh,
    const int* __restrict__ topk, const float* __restrict__ base,
    float* __restrict__ dctx)
{
    const int bh = blockIdx.x;
    const int tid = threadIdx.x;
    const int w = tid >> 6, lane = tid & 63;
    const float* Q = qh + (size_t)bh * L * HD;
    const float* K = kh + (size_t)bh * L * HD;
    const float* V = vh + (size_t)bh * L * HD;
    __shared__ int idx_s[TOPU];
    __shared__ float Qs[TOPU][HD];
    __shared__ float Ks[64][65];
    __shared__ float Vs[64][65];
    if (tid < TOPU) idx_s[tid] = topk[bh * TOPU + tid];
    __syncthreads();
    for (int e = tid; e < TOPU * HD; e += 256) {
        int u = e >> 6, d = e & 63;
        Qs[u][d] = Q[(size_t)idx_s[u] * HD + d];
    }
    float m[10], lsum[10], acc[10];
#pragma unroll
    for (int u = 0; u < 10; u++) { m[u] = NEG_INF; lsum[u] = 0.f; acc[u] = 0.f; }
    __syncthreads();
    for (int k0 = 0; k0 < L; k0 += 64) {
        for (int e = tid; e < 64 * HD; e += 256) {
            int r = e >> 6, c = e & 63;
            Ks[r][c] = K[(size_t)(k0 + r) * HD + c];
            Vs[r][c] = V[(size_t)(k0 + r) * HD + c];
        }
        __syncthreads();
#pragma unroll
        for (int u = 0; u < 10; u++) {
            const int qq = w * 10 + u;
            float s = 0;
#pragma unroll
            for (int d = 0; d < HD; d++) s += Qs[qq][d] * Ks[lane][d];
            s *= SCALE;
            float tmax = s;
#pragma unroll
            for (int off = 32; off >= 1; off >>= 1) tmax = fmaxf(tmax, __shfl_xor(tmax, off));
            float mnew = fmaxf(m[u], tmax);
            float alpha = expf(m[u] - mnew);
            float p = expf(s - mnew);
            float psum = p;
#pragma unroll
            for (int off = 32; off >= 1; off >>= 1) psum += __shfl_xor(psum, off);
            lsum[u] = lsum[u] * alpha + psum;
            float a = acc[u] * alpha;
            for (int k = 0; k < 64; k++) {
                float pk = __shfl(p, k);
                a += pk * Vs[k][lane];
            }
            acc[u] = a;
            m[u] = mnew;
        }
        __syncthreads();
    }
#pragma unroll
    for (int u = 0; u < 10; u++) {
        int uu = w * 10 + u;
        dctx[((size_t)bh * TOPU + uu) * HD + lane] = acc[u] / lsum[u] - base[bh * HD + lane];
    }
}

// ---------------------------------------------------------------------------
// base_out[b][j] = bo[j] + sum_d base_flat[b][d] * Wo[j][d]   (j in [0,1024))
// ---------------------------------------------------------------------------
__global__ __launch_bounds__(256) void base_out_kernel(const float* __restrict__ base,
    const float* __restrict__ Wo, const float* __restrict__ bo, float* __restrict__ bout)
{
    const int blk = blockIdx.x;
    const int b = blk >> 4;
    const int j0 = (blk & 15) * 64;
    const int tid = threadIdx.x;
    const int w = tid >> 6, lane = tid & 63;
    float bf[16];
#pragma unroll
    for (int t = 0; t < 16; t++) bf[t] = base[b * DM + lane + 64 * t];
    for (int jj = w; jj < 64; jj += 4) {
        int j = j0 + jj;
        float s = 0;
#pragma unroll
        for (int t = 0; t < 16; t++) s += bf[t] * Wo[(size_t)j * DM + lane + 64 * t];
#pragma unroll
        for (int off = 32; off >= 1; off >>= 1) s += __shfl_xor(s, off);
        if (lane == 0) bout[b * DM + j] = s + bo[j];
    }
}

// ---------------------------------------------------------------------------
// out[b,l,:] = base_out[b,:]  (broadcast fill, float4)
// ---------------------------------------------------------------------------
__global__ void fill_kernel(const float* __restrict__ bout, float* __restrict__ out)
{
    size_t i = (size_t)blockIdx.x * blockDim.x + threadIdx.x;
    const size_t total = (size_t)BATCH * L * DM / 4;
    if (i >= total) return;
    int j4 = (int)(i & (DM / 4 - 1));
    int b = (int)(i / ((size_t)L * DM / 4));
    ((float4*)out)[i] = ((const float4*)bout)[b * (DM / 4) + j4];
}

// ---------------------------------------------------------------------------
// out[b,l,:] += dctx[b,h,u,:] @ Wo[:, h*64:(h+1)*64]^T for each selected row.
// One block per (bh,u); wave-per-j 64-wide dot + atomicAdd.
// ---------------------------------------------------------------------------
__global__ __launch_bounds__(256) void corr_kernel(const int* __restrict__ topk,
    const float* __restrict__ dctx, const float* __restrict__ Wo, float* __restrict__ out)
{
    const int g = blockIdx.x;
    const int bh = g / TOPU;
    const int b = bh >> 4, h = bh & 15;
    const int tid = threadIdx.x;
    const int w = tid >> 6, lane = tid & 63;
    const int l = topk[g];
    float dc = dctx[(size_t)g * HD + lane];
    float* orow = out + ((size_t)b * L + l) * DM;
    for (int j = w; j < DM; j += 4) {
        float s = dc * Wo[(size_t)j * DM + h * HD + lane];
#pragma unroll
        for (int off = 32; off >= 1; off >>= 1) s += __shfl_xor(s, off);
        if (lane == 0) atomicAdd(orow + j, s);
    }
}

extern "C" void kernel_launch(void* const* d_in, const int* in_sizes, int n_in,
                              void* d_out, int out_size, void* d_ws, size_t ws_size,
                              hipStream_t stream)
{
    const float* query = (const float*)d_in[0];
    const float* key   = (const float*)d_in[1];
    const float* value = (const float*)d_in[2];
    const float* Wq = (const float*)d_in[3];
    const float* bq = (const float*)d_in[4];
    const float* Wk = (const float*)d_in[5];
    const float* bk = (const float*)d_in[6];
    const float* Wv = (const float*)d_in[7];
    const float* bv = (const float*)d_in[8];
    const float* Wo = (const float*)d_in[9];
    const float* bo = (const float*)d_in[10];
    float* out = (float*)d_out;

    float* ws = (float*)d_ws;
    const size_t headsz = (size_t)BATCH * NH * L * HD;  // 4,194,304
    float* qh   = ws;
    float* kh   = qh + headsz;
    float* vh   = kh + headsz;
    float* sp   = vh + headsz;                    // B*NH*L = 65536
    float* base = sp + (size_t)BATCH * NH * L;    // B*NH*64 = 2048
    float* dctx = base + BATCH * NH * HD;         // B*NH*40*64 = 163840
    float* bout = dctx + (size_t)BATCH * NH * TOPU * HD;  // B*1024 = 2048
    int*   topk = (int*)(bout + BATCH * DM);      // B*NH*40 = 1280 ints

    dim3 gproj(16, 64);
    proj_kernel<<<gproj, 256, 0, stream>>>(query, Wq, bq, qh);
    proj_kernel<<<gproj, 256, 0, stream>>>(key,   Wk, bk, kh);
    proj_kernel<<<gproj, 256, 0, stream>>>(value, Wv, bv, vh);

    sparsity_kernel<<<dim3(BATCH * NH, L / 64), 256, 0, stream>>>(qh, kh, sp);
    base_kernel<<<BATCH * NH, 256, 0, stream>>>(vh, base);
    topk_kernel<<<BATCH * NH, 256, 0, stream>>>(sp, topk);
    attn_top_kernel<<<BATCH * NH, 256, 0, stream>>>(qh, kh, vh, topk, base, dctx);
    base_out_kernel<<<BATCH * 16, 256, 0, stream>>>(base, Wo, bo, bout);
    fill_kernel<<<(int)(((size_t)BATCH * L * DM / 4 + 255) / 256), 256, 0, stream>>>(bout, out);
    corr_kernel<<<BATCH * NH * TOPU, 256, 0, stream>>>(topk, dctx, Wo, out);
}

// Round 2
// 808.793 us; speedup vs baseline: 2.1897x; 2.1897x over previous
//
#include <hip/hip_runtime.h>
#include <math.h>

#define L 2048
#define DM 1024
#define HD 64
#define NH 16
#define BATCH 2
#define TOPU 40
#define SCALE 0.125f
#define NEG_INF (-1e30f)

typedef short s8v __attribute__((ext_vector_type(8)));
typedef short s4v __attribute__((ext_vector_type(4)));
typedef float f32x4 __attribute__((ext_vector_type(4)));

// bf16 round-to-nearest-even split helpers (bit-level, avoids type issues)
__device__ inline short f2bf(float x) {
    union { float f; unsigned u; } v; v.f = x;
    unsigned r = v.u + 0x7FFFu + ((v.u >> 16) & 1u);
    return (short)(r >> 16);
}
__device__ inline float bf2f(short b) {
    union { unsigned u; float f; } v; v.u = ((unsigned)(unsigned short)b) << 16;
    return v.f;
}

// ---------------------------------------------------------------------------
// Split fp32 -> bf16 hi + bf16 lo (Markidis split). float4-vectorized.
// ---------------------------------------------------------------------------
__global__ __launch_bounds__(256) void split_kernel(const float4* __restrict__ in,
    short* __restrict__ hi, short* __restrict__ lo, int n4)
{
    int i = blockIdx.x * 256 + threadIdx.x;
    if (i >= n4) return;
    float4 x = in[i];
    float xs[4] = {x.x, x.y, x.z, x.w};
    s4v h, l;
#pragma unroll
    for (int j = 0; j < 4; ++j) {
        short hh = f2bf(xs[j]);
        h[j] = hh;
        l[j] = f2bf(xs[j] - bf2f(hh));
    }
    *(s4v*)&hi[(size_t)i * 4] = h;
    *(s4v*)&lo[(size_t)i * 4] = l;
}

// ---------------------------------------------------------------------------
// Split-bf16 MFMA projection GEMM (NT): Y = X @ W^T + bias.
// X[4096][1024], W[1024][1024] as hi/lo bf16. 128x128 tile, BK=32, 4 waves,
// each wave 64x64 (4x4 frags of 16x16x32). LDS rows padded 32->40 shorts.
// Output written to head layout [(b,h)][L][64] fp32, optionally split bf16.
// ---------------------------------------------------------------------------
__global__ __launch_bounds__(256) void proj_mfma_kernel(
    const short* __restrict__ Xhi, const short* __restrict__ Xlo,
    const short* __restrict__ Whi, const short* __restrict__ Wlo,
    const float* __restrict__ bias, float* __restrict__ Y,
    short* __restrict__ Yhi, short* __restrict__ Ylo)
{
    __shared__ short Ah[128 * 40], Al[128 * 40], Bh[128 * 40], Bl[128 * 40];
    const int i0 = blockIdx.y * 128, j0 = blockIdx.x * 128;
    const int tid = threadIdx.x;
    const int wid = tid >> 6, lane = tid & 63;
    const int wm = wid >> 1, wn = wid & 1;
    const int lr = lane & 15, lk = lane >> 4;
    f32x4 acc[4][4];
    f32x4 zero = {0.f, 0.f, 0.f, 0.f};
#pragma unroll
    for (int m = 0; m < 4; ++m)
#pragma unroll
        for (int n = 0; n < 4; ++n) acc[m][n] = zero;

    for (int k0 = 0; k0 < DM; k0 += 32) {
        __syncthreads();
#pragma unroll
        for (int q = 0; q < 8; ++q) {
            const int arr = q >> 1;                    // compile-time per q
            const int rem = tid + ((q & 1) << 8);
            const int row = rem >> 2, part = rem & 3;
            const short* src = (arr == 0) ? Xhi : (arr == 1) ? Xlo : (arr == 2) ? Whi : Wlo;
            const int gr = ((arr < 2) ? i0 : j0) + row;
            s8v v = *(const s8v*)&src[(size_t)gr * DM + k0 + part * 8];
            short* dst = (arr == 0) ? Ah : (arr == 1) ? Al : (arr == 2) ? Bh : Bl;
            *(s8v*)&dst[row * 40 + part * 8] = v;
        }
        __syncthreads();
        s8v af_h[4], af_l[4];
#pragma unroll
        for (int m = 0; m < 4; ++m) {
            int r = wm * 64 + m * 16 + lr;
            af_h[m] = *(const s8v*)&Ah[r * 40 + lk * 8];
            af_l[m] = *(const s8v*)&Al[r * 40 + lk * 8];
        }
#pragma unroll
        for (int n = 0; n < 4; ++n) {
            int r = wn * 64 + n * 16 + lr;
            s8v bf_h = *(const s8v*)&Bh[r * 40 + lk * 8];
            s8v bf_l = *(const s8v*)&Bl[r * 40 + lk * 8];
#pragma unroll
            for (int m = 0; m < 4; ++m) {
                acc[m][n] = __builtin_amdgcn_mfma_f32_16x16x32_bf16(af_h[m], bf_h, acc[m][n], 0, 0, 0);
                acc[m][n] = __builtin_amdgcn_mfma_f32_16x16x32_bf16(af_h[m], bf_l, acc[m][n], 0, 0, 0);
                acc[m][n] = __builtin_amdgcn_mfma_f32_16x16x32_bf16(af_l[m], bf_h, acc[m][n], 0, 0, 0);
            }
        }
    }
    // C/D layout: col = lane&15 (N), row = (lane>>4)*4 + reg (M)  [m89/m91]
#pragma unroll
    for (int m = 0; m < 4; ++m)
#pragma unroll
        for (int n = 0; n < 4; ++n)
#pragma unroll
            for (int rg = 0; rg < 4; ++rg) {
                int i = i0 + wm * 64 + m * 16 + lk * 4 + rg;
                int j = j0 + wn * 64 + n * 16 + lr;
                float val = acc[m][n][rg] + bias[j];
                int b = i >> 11, l = i & (L - 1);
                int h = j >> 6, dd = j & 63;
                size_t idx = (((size_t)(b * NH + h)) * L + l) * HD + dd;
                Y[idx] = val;
                if (Yhi) {
                    short hh = f2bf(val);
                    Yhi[idx] = hh;
                    Ylo[idx] = f2bf(val - bf2f(hh));
                }
            }
}

// ---------------------------------------------------------------------------
// Sparsity via split-bf16 MFMA: per (bh, 64-query tile) compute
// scale*(max_k S - sum_k S / L) over all 2048 keys. Wave = 16 queries.
// K staged in LDS 128-key chunks, rows padded 64->72 shorts.
// ---------------------------------------------------------------------------
__global__ __launch_bounds__(256) void sparsity_mfma_kernel(
    const short* __restrict__ qhi, const short* __restrict__ qlo,
    const short* __restrict__ khi, const short* __restrict__ klo,
    float* __restrict__ sp)
{
    __shared__ short Kh[128 * 72], Kl[128 * 72];
    const int bh = blockIdx.x, q0 = blockIdx.y * 64;
    const int tid = threadIdx.x;
    const int w = tid >> 6, lane = tid & 63;
    const int lr = lane & 15, lk = lane >> 4;
    const size_t qbase = ((size_t)bh * L + q0 + w * 16 + lr) * HD;
    s8v qf_h[2], qf_l[2];
#pragma unroll
    for (int s = 0; s < 2; ++s) {
        qf_h[s] = *(const s8v*)&qhi[qbase + s * 32 + lk * 8];
        qf_l[s] = *(const s8v*)&qlo[qbase + s * 32 + lk * 8];
    }
    float vmax[4] = {NEG_INF, NEG_INF, NEG_INF, NEG_INF};
    float vsum[4] = {0.f, 0.f, 0.f, 0.f};
    for (int kc = 0; kc < L; kc += 128) {
        __syncthreads();
#pragma unroll
        for (int q = 0; q < 8; ++q) {
            const int arr = q >> 2;                    // compile-time per q
            const int rem = tid + ((q & 3) << 8);
            const int row = rem >> 3, part = rem & 7;
            const short* src = arr ? klo : khi;
            s8v v = *(const s8v*)&src[((size_t)bh * L + kc + row) * HD + part * 8];
            short* dst = arr ? Kl : Kh;
            *(s8v*)&dst[row * 72 + part * 8] = v;
        }
        __syncthreads();
#pragma unroll
        for (int kt = 0; kt < 8; ++kt) {
            int krow = kt * 16 + lr;
            s8v b0h = *(const s8v*)&Kh[krow * 72 + lk * 8];
            s8v b0l = *(const s8v*)&Kl[krow * 72 + lk * 8];
            s8v b1h = *(const s8v*)&Kh[krow * 72 + 32 + lk * 8];
            s8v b1l = *(const s8v*)&Kl[krow * 72 + 32 + lk * 8];
            f32x4 c = {0.f, 0.f, 0.f, 0.f};
            c = __builtin_amdgcn_mfma_f32_16x16x32_bf16(qf_h[0], b0h, c, 0, 0, 0);
            c = __builtin_amdgcn_mfma_f32_16x16x32_bf16(qf_h[0], b0l, c, 0, 0, 0);
            c = __builtin_amdgcn_mfma_f32_16x16x32_bf16(qf_l[0], b0h, c, 0, 0, 0);
            c = __builtin_amdgcn_mfma_f32_16x16x32_bf16(qf_h[1], b1h, c, 0, 0, 0);
            c = __builtin_amdgcn_mfma_f32_16x16x32_bf16(qf_h[1], b1l, c, 0, 0, 0);
            c = __builtin_amdgcn_mfma_f32_16x16x32_bf16(qf_l[1], b1h, c, 0, 0, 0);
#pragma unroll
            for (int r = 0; r < 4; ++r) {
                vmax[r] = fmaxf(vmax[r], c[r]);
                vsum[r] += c[r];
            }
        }
    }
#pragma unroll
    for (int off = 1; off < 16; off <<= 1)
#pragma unroll
        for (int r = 0; r < 4; ++r) {
            vmax[r] = fmaxf(vmax[r], __shfl_xor(vmax[r], off));
            vsum[r] += __shfl_xor(vsum[r], off);
        }
    if (lr == 0)
#pragma unroll
        for (int r = 0; r < 4; ++r)
            sp[(size_t)bh * L + q0 + w * 16 + lk * 4 + r] =
                SCALE * (vmax[r] - vsum[r] * (1.0f / (float)L));
}

// ---------------------------------------------------------------------------
// base[b,h,d] = mean_l vh[b,h,l,d]
// ---------------------------------------------------------------------------
__global__ __launch_bounds__(256) void base_kernel(const float* __restrict__ vh,
                                                   float* __restrict__ base)
{
    const int bh = blockIdx.x;
    const int tid = threadIdx.x;
    const int d = tid & 63, lg = tid >> 6;
    const float* V = vh + (size_t)bh * L * HD;
    float s = 0;
    for (int l = lg; l < L; l += 4) s += V[(size_t)l * HD + d];
    __shared__ float red[256];
    red[tid] = s;
    __syncthreads();
    if (tid < 64)
        base[bh * HD + d] = (red[d] + red[64 + d] + red[128 + d] + red[192 + d]) * (1.0f / (float)L);
}

// ---------------------------------------------------------------------------
// top-40 indices of sparsity per (b,h). Iterative argmax, tie -> lower index.
// ---------------------------------------------------------------------------
__global__ __launch_bounds__(256) void topk_kernel(const float* __restrict__ sp,
                                                   int* __restrict__ topk)
{
    const int bh = blockIdx.x;
    __shared__ float vals[L];
    __shared__ float rv[256];
    __shared__ int ri[256];
    const int tid = threadIdx.x;
    for (int i = 0; i < L / 256; i++) vals[tid + 256 * i] = sp[(size_t)bh * L + tid + 256 * i];
    __syncthreads();
    for (int it = 0; it < TOPU; it++) {
        float bv = NEG_INF;
        int bi = L;
        for (int i = 0; i < L / 256; i++) {
            int idx = tid + 256 * i;
            float v = vals[idx];
            if (v > bv || (v == bv && idx < bi)) { bv = v; bi = idx; }
        }
        rv[tid] = bv; ri[tid] = bi;
        __syncthreads();
        for (int s = 128; s > 0; s >>= 1) {
            if (tid < s) {
                if (rv[tid + s] > rv[tid] ||
                    (rv[tid + s] == rv[tid] && ri[tid + s] < ri[tid])) {
                    rv[tid] = rv[tid + s]; ri[tid] = ri[tid + s];
                }
            }
            __syncthreads();
        }
        if (tid == 0) { topk[bh * TOPU + it] = ri[0]; vals[ri[0]] = NEG_INF; }
        __syncthreads();
    }
}

// ---------------------------------------------------------------------------
// Flash attention partials for the 40 selected queries, keys split 8 ways.
// grid (bh, chunk). Writes per-chunk (m, l, acc).
// ---------------------------------------------------------------------------
__global__ __launch_bounds__(256) void attn_part_kernel(const float* __restrict__ qh,
    const float* __restrict__ kh, const float* __restrict__ vh,
    const int* __restrict__ topk,
    float* __restrict__ pm, float* __restrict__ pl, float* __restrict__ pacc)
{
    const int bh = blockIdx.x, chunk = blockIdx.y;
    const int tid = threadIdx.x;
    const int w = tid >> 6, lane = tid & 63;
    const float* Q = qh + (size_t)bh * L * HD;
    const float* K = kh + (size_t)bh * L * HD;
    const float* V = vh + (size_t)bh * L * HD;
    __shared__ int idx_s[TOPU];
    __shared__ float Qs[TOPU][HD];
    __shared__ float Ks[64][65];
    __shared__ float Vs[64][65];
    if (tid < TOPU) idx_s[tid] = topk[bh * TOPU + tid];
    __syncthreads();
    for (int e = tid; e < TOPU * HD; e += 256) {
        int u = e >> 6, d = e & 63;
        Qs[u][d] = Q[(size_t)idx_s[u] * HD + d];
    }
    float m[10], lsum[10], acc[10];
#pragma unroll
    for (int u = 0; u < 10; u++) { m[u] = NEG_INF; lsum[u] = 0.f; acc[u] = 0.f; }
    __syncthreads();
    const int kbase = chunk * (L / 8);
    for (int k0 = kbase; k0 < kbase + L / 8; k0 += 64) {
        for (int e = tid; e < 64 * HD; e += 256) {
            int r = e >> 6, c = e & 63;
            Ks[r][c] = K[(size_t)(k0 + r) * HD + c];
            Vs[r][c] = V[(size_t)(k0 + r) * HD + c];
        }
        __syncthreads();
#pragma unroll
        for (int u = 0; u < 10; u++) {
            const int qq = w * 10 + u;
            float s = 0;
#pragma unroll
            for (int d = 0; d < HD; d++) s += Qs[qq][d] * Ks[lane][d];
            s *= SCALE;
            float tmax = s;
#pragma unroll
            for (int off = 32; off >= 1; off >>= 1) tmax = fmaxf(tmax, __shfl_xor(tmax, off));
            float mnew = fmaxf(m[u], tmax);
            float alpha = expf(m[u] - mnew);
            float p = expf(s - mnew);
            float psum = p;
#pragma unroll
            for (int off = 32; off >= 1; off >>= 1) psum += __shfl_xor(psum, off);
            lsum[u] = lsum[u] * alpha + psum;
            float a = acc[u] * alpha;
            for (int k = 0; k < 64; k++) {
                float pk = __shfl(p, k);
                a += pk * Vs[k][lane];
            }
            acc[u] = a;
            m[u] = mnew;
        }
        __syncthreads();
    }
#pragma unroll
    for (int u = 0; u < 10; u++) {
        int uu = w * 10 + u;
        size_t pidx = (size_t)(bh * 8 + chunk) * TOPU + uu;
        pacc[pidx * HD + lane] = acc[u];
        if (lane == 0) { pm[pidx] = m[u]; pl[pidx] = lsum[u]; }
    }
}

// ---------------------------------------------------------------------------
// Combine 8 chunk-partials -> dctx = softmax ctx - base.
// ---------------------------------------------------------------------------
__global__ __launch_bounds__(256) void attn_combine_kernel(const float* __restrict__ pm,
    const float* __restrict__ pl, const float* __restrict__ pacc,
    const float* __restrict__ base, float* __restrict__ dctx)
{
    const int bh = blockIdx.x;
    const int tid = threadIdx.x;
    const int w = tid >> 6, lane = tid & 63;
    for (int u = w * 10; u < w * 10 + 10; ++u) {
        float mstar = NEG_INF;
#pragma unroll
        for (int c = 0; c < 8; ++c)
            mstar = fmaxf(mstar, pm[(size_t)(bh * 8 + c) * TOPU + u]);
        float av = 0.f, lv = 0.f;
#pragma unroll
        for (int c = 0; c < 8; ++c) {
            size_t pidx = (size_t)(bh * 8 + c) * TOPU + u;
            float al = expf(pm[pidx] - mstar);
            lv += al * pl[pidx];
            av += al * pacc[pidx * HD + lane];
        }
        dctx[((size_t)bh * TOPU + u) * HD + lane] = av / lv - base[bh * HD + lane];
    }
}

// ---------------------------------------------------------------------------
// base_out[b][j] = bo[j] + sum_d base_flat[b][d] * Wo[j][d]
// ---------------------------------------------------------------------------
__global__ __launch_bounds__(256) void base_out_kernel(const float* __restrict__ base,
    const float* __restrict__ Wo, const float* __restrict__ bo, float* __restrict__ bout)
{
    const int blk = blockIdx.x;
    const int b = blk >> 4;
    const int j0 = (blk & 15) * 64;
    const int tid = threadIdx.x;
    const int w = tid >> 6, lane = tid & 63;
    float bf[16];
#pragma unroll
    for (int t = 0; t < 16; t++) bf[t] = base[b * DM + lane + 64 * t];
    for (int jj = w; jj < 64; jj += 4) {
        int j = j0 + jj;
        float s = 0;
#pragma unroll
        for (int t = 0; t < 16; t++) s += bf[t] * Wo[(size_t)j * DM + lane + 64 * t];
#pragma unroll
        for (int off = 32; off >= 1; off >>= 1) s += __shfl_xor(s, off);
        if (lane == 0) bout[b * DM + j] = s + bo[j];
    }
}

// ---------------------------------------------------------------------------
// out[b,l,:] = base_out[b,:]  (broadcast fill, float4)
// ---------------------------------------------------------------------------
__global__ void fill_kernel(const float* __restrict__ bout, float* __restrict__ out)
{
    size_t i = (size_t)blockIdx.x * blockDim.x + threadIdx.x;
    const size_t total = (size_t)BATCH * L * DM / 4;
    if (i >= total) return;
    int j4 = (int)(i & (DM / 4 - 1));
    int b = (int)(i / ((size_t)L * DM / 4));
    ((float4*)out)[i] = ((const float4*)bout)[b * (DM / 4) + j4];
}

// ---------------------------------------------------------------------------
// out[b,l,:] += dctx[b,h,u,:] @ Wo[:, h*64:(h+1)*64]^T for each selected row.
// ---------------------------------------------------------------------------
__global__ __launch_bounds__(256) void corr_kernel(const int* __restrict__ topk,
    const float* __restrict__ dctx, const float* __restrict__ Wo, float* __restrict__ out)
{
    const int g = blockIdx.x;
    const int bh = g / TOPU;
    const int b = bh >> 4, h = bh & 15;
    const int tid = threadIdx.x;
    const int w = tid >> 6, lane = tid & 63;
    const int l = topk[g];
    float dc = dctx[(size_t)g * HD + lane];
    float* orow = out + ((size_t)b * L + l) * DM;
    for (int j = w; j < DM; j += 4) {
        float s = dc * Wo[(size_t)j * DM + h * HD + lane];
#pragma unroll
        for (int off = 32; off >= 1; off >>= 1) s += __shfl_xor(s, off);
        if (lane == 0) atomicAdd(orow + j, s);
    }
}

extern "C" void kernel_launch(void* const* d_in, const int* in_sizes, int n_in,
                              void* d_out, int out_size, void* d_ws, size_t ws_size,
                              hipStream_t stream)
{
    const float* query = (const float*)d_in[0];
    const float* key   = (const float*)d_in[1];
    const float* value = (const float*)d_in[2];
    const float* Wq = (const float*)d_in[3];
    const float* bq = (const float*)d_in[4];
    const float* Wk = (const float*)d_in[5];
    const float* bk = (const float*)d_in[6];
    const float* Wv = (const float*)d_in[7];
    const float* bv = (const float*)d_in[8];
    const float* Wo = (const float*)d_in[9];
    const float* bo = (const float*)d_in[10];
    float* out = (float*)d_out;

    const size_t headsz = (size_t)BATCH * NH * L * HD;  // 4,194,304
    const size_t wsz    = (size_t)DM * DM;              // 1,048,576

    float* ws = (float*)d_ws;
    float* qh   = ws;
    float* kh   = qh + headsz;
    float* vh   = kh + headsz;
    float* sp   = vh + headsz;                       // 65536
    float* base = sp + (size_t)BATCH * NH * L;       // 2048
    float* dctx = base + BATCH * NH * HD;            // 81920
    float* bout = dctx + (size_t)BATCH * NH * TOPU * HD;
    int*   topk = (int*)(bout + BATCH * DM);         // 1280 ints
    float* pm   = (float*)(topk + 1280);             // 10240
    float* pl   = pm + (size_t)BATCH * NH * 8 * TOPU;
    float* pacc = pl + (size_t)BATCH * NH * 8 * TOPU;  // 655360
    short* qhi  = (short*)(pacc + (size_t)BATCH * NH * 8 * TOPU * HD);
    short* qlo  = qhi + headsz;
    short* khi  = qlo + headsz;
    short* klo  = khi + headsz;
    short* xin_hi = klo + headsz;                    // reused per projection
    short* xin_lo = xin_hi + headsz;
    short* w_hi   = xin_lo + headsz;                 // reused per projection
    short* w_lo   = w_hi + wsz;

    const int n4_in = (int)(headsz / 4);             // 1,048,576
    const int n4_w  = (int)(wsz / 4);                // 262,144
    dim3 gproj(8, 32);

    // Q projection
    split_kernel<<<(n4_w + 255) / 256, 256, 0, stream>>>((const float4*)Wq, w_hi, w_lo, n4_w);
    split_kernel<<<(n4_in + 255) / 256, 256, 0, stream>>>((const float4*)query, xin_hi, xin_lo, n4_in);
    proj_mfma_kernel<<<gproj, 256, 0, stream>>>(xin_hi, xin_lo, w_hi, w_lo, bq, qh, qhi, qlo);
    // K projection
    split_kernel<<<(n4_w + 255) / 256, 256, 0, stream>>>((const float4*)Wk, w_hi, w_lo, n4_w);
    split_kernel<<<(n4_in + 255) / 256, 256, 0, stream>>>((const float4*)key, xin_hi, xin_lo, n4_in);
    proj_mfma_kernel<<<gproj, 256, 0, stream>>>(xin_hi, xin_lo, w_hi, w_lo, bk, kh, khi, klo);
    // V projection (no split output needed)
    split_kernel<<<(n4_w + 255) / 256, 256, 0, stream>>>((const float4*)Wv, w_hi, w_lo, n4_w);
    split_kernel<<<(n4_in + 255) / 256, 256, 0, stream>>>((const float4*)value, xin_hi, xin_lo, n4_in);
    proj_mfma_kernel<<<gproj, 256, 0, stream>>>(xin_hi, xin_lo, w_hi, w_lo, bv, vh, (short*)0, (short*)0);

    sparsity_mfma_kernel<<<dim3(BATCH * NH, L / 64), 256, 0, stream>>>(qhi, qlo, khi, klo, sp);
    base_kernel<<<BATCH * NH, 256, 0, stream>>>(vh, base);
    topk_kernel<<<BATCH * NH, 256, 0, stream>>>(sp, topk);
    attn_part_kernel<<<dim3(BATCH * NH, 8), 256, 0, stream>>>(qh, kh, vh, topk, pm, pl, pacc);
    attn_combine_kernel<<<BATCH * NH, 256, 0, stream>>>(pm, pl, pacc, base, dctx);
    base_out_kernel<<<BATCH * 16, 256, 0, stream>>>(base, Wo, bo, bout);
    fill_kernel<<<(int)(((size_t)BATCH * L * DM / 4 + 255) / 256), 256, 0, stream>>>(bout, out);
    corr_kernel<<<BATCH * NH * TOPU, 256, 0, stream>>>(topk, dctx, Wo, out);
}

// Round 4
// 633.614 us; speedup vs baseline: 2.7951x; 1.2765x over previous
//
#include <hip/hip_runtime.h>
#include <math.h>

#define L 2048
#define DM 1024
#define HD 64
#define NH 16
#define BATCH 2
#define TOPU 40
#define SCALE 0.125f
#define NEG_INF (-1e30f)

typedef short s8v __attribute__((ext_vector_type(8)));
typedef short s4v __attribute__((ext_vector_type(4)));
typedef float f32x4 __attribute__((ext_vector_type(4)));

// bf16 round-to-nearest-even split helpers (bit-level, avoids type issues)
__device__ inline short f2bf(float x) {
    union { float f; unsigned u; } v; v.f = x;
    unsigned r = v.u + 0x7FFFu + ((v.u >> 16) & 1u);
    return (short)(r >> 16);
}
__device__ inline float bf2f(short b) {
    union { unsigned u; float f; } v; v.u = ((unsigned)(unsigned short)b) << 16;
    return v.f;
}

// ---------------------------------------------------------------------------
// Split fp32 -> bf16 hi + bf16 lo (Markidis split). float4-vectorized.
// ---------------------------------------------------------------------------
__global__ __launch_bounds__(256) void split_kernel(const float4* __restrict__ in,
    short* __restrict__ hi, short* __restrict__ lo, int n4)
{
    int i = blockIdx.x * 256 + threadIdx.x;
    if (i >= n4) return;
    float4 x = in[i];
    float xs[4] = {x.x, x.y, x.z, x.w};
    s4v h, l;
#pragma unroll
    for (int j = 0; j < 4; ++j) {
        short hh = f2bf(xs[j]);
        h[j] = hh;
        l[j] = f2bf(xs[j] - bf2f(hh));
    }
    *(s4v*)&hi[(size_t)i * 4] = h;
    *(s4v*)&lo[(size_t)i * 4] = l;
}

// ---------------------------------------------------------------------------
// Split-bf16 MFMA projection GEMM (NT): Y = X @ W^T + bias.
// X[4096][1024], W[1024][1024] as hi/lo bf16. 128x128 tile, BK=32, 4 waves,
// each wave 64x64 (4x4 frags of 16x16x32). LDS rows padded 32->40 shorts.
// ---------------------------------------------------------------------------
__global__ __launch_bounds__(256) void proj_mfma_kernel(
    const short* __restrict__ Xhi, const short* __restrict__ Xlo,
    const short* __restrict__ Whi, const short* __restrict__ Wlo,
    const float* __restrict__ bias, float* __restrict__ Y,
    short* __restrict__ Yhi, short* __restrict__ Ylo)
{
    __shared__ short Ah[128 * 40], Al[128 * 40], Bh[128 * 40], Bl[128 * 40];
    const int i0 = blockIdx.y * 128, j0 = blockIdx.x * 128;
    const int tid = threadIdx.x;
    const int wid = tid >> 6, lane = tid & 63;
    const int wm = wid >> 1, wn = wid & 1;
    const int lr = lane & 15, lk = lane >> 4;
    f32x4 acc[4][4];
    f32x4 zero = {0.f, 0.f, 0.f, 0.f};
#pragma unroll
    for (int m = 0; m < 4; ++m)
#pragma unroll
        for (int n = 0; n < 4; ++n) acc[m][n] = zero;

    for (int k0 = 0; k0 < DM; k0 += 32) {
        __syncthreads();
#pragma unroll
        for (int q = 0; q < 8; ++q) {
            const int arr = q >> 1;                    // compile-time per q
            const int rem = tid + ((q & 1) << 8);
            const int row = rem >> 2, part = rem & 3;
            const short* src = (arr == 0) ? Xhi : (arr == 1) ? Xlo : (arr == 2) ? Whi : Wlo;
            const int gr = ((arr < 2) ? i0 : j0) + row;
            s8v v = *(const s8v*)&src[(size_t)gr * DM + k0 + part * 8];
            short* dst = (arr == 0) ? Ah : (arr == 1) ? Al : (arr == 2) ? Bh : Bl;
            *(s8v*)&dst[row * 40 + part * 8] = v;
        }
        __syncthreads();
        s8v af_h[4], af_l[4];
#pragma unroll
        for (int m = 0; m < 4; ++m) {
            int r = wm * 64 + m * 16 + lr;
            af_h[m] = *(const s8v*)&Ah[r * 40 + lk * 8];
            af_l[m] = *(const s8v*)&Al[r * 40 + lk * 8];
        }
#pragma unroll
        for (int n = 0; n < 4; ++n) {
            int r = wn * 64 + n * 16 + lr;
            s8v bf_h = *(const s8v*)&Bh[r * 40 + lk * 8];
            s8v bf_l = *(const s8v*)&Bl[r * 40 + lk * 8];
#pragma unroll
            for (int m = 0; m < 4; ++m) {
                acc[m][n] = __builtin_amdgcn_mfma_f32_16x16x32_bf16(af_h[m], bf_h, acc[m][n], 0, 0, 0);
                acc[m][n] = __builtin_amdgcn_mfma_f32_16x16x32_bf16(af_h[m], bf_l, acc[m][n], 0, 0, 0);
                acc[m][n] = __builtin_amdgcn_mfma_f32_16x16x32_bf16(af_l[m], bf_h, acc[m][n], 0, 0, 0);
            }
        }
    }
    // C/D layout: col = lane&15 (N), row = (lane>>4)*4 + reg (M)  [m89/m91]
#pragma unroll
    for (int m = 0; m < 4; ++m)
#pragma unroll
        for (int n = 0; n < 4; ++n)
#pragma unroll
            for (int rg = 0; rg < 4; ++rg) {
                int i = i0 + wm * 64 + m * 16 + lk * 4 + rg;
                int j = j0 + wn * 64 + n * 16 + lr;
                float val = acc[m][n][rg] + bias[j];
                int b = i >> 11, l = i & (L - 1);
                int h = j >> 6, dd = j & 63;
                size_t idx = (((size_t)(b * NH + h)) * L + l) * HD + dd;
                Y[idx] = val;
                if (Yhi) {
                    short hh = f2bf(val);
                    Yhi[idx] = hh;
                    Ylo[idx] = f2bf(val - bf2f(hh));
                }
            }
}

// ---------------------------------------------------------------------------
// Sparsity via split-bf16 MFMA: per (bh, 64-query tile) compute
// scale*(max_k S - sum_k S / L) over all 2048 keys.
// ---------------------------------------------------------------------------
__global__ __launch_bounds__(256) void sparsity_mfma_kernel(
    const short* __restrict__ qhi, const short* __restrict__ qlo,
    const short* __restrict__ khi, const short* __restrict__ klo,
    float* __restrict__ sp)
{
    __shared__ short Kh[128 * 72], Kl[128 * 72];
    const int bh = blockIdx.x, q0 = blockIdx.y * 64;
    const int tid = threadIdx.x;
    const int w = tid >> 6, lane = tid & 63;
    const int lr = lane & 15, lk = lane >> 4;
    const size_t qbase = ((size_t)bh * L + q0 + w * 16 + lr) * HD;
    s8v qf_h[2], qf_l[2];
#pragma unroll
    for (int s = 0; s < 2; ++s) {
        qf_h[s] = *(const s8v*)&qhi[qbase + s * 32 + lk * 8];
        qf_l[s] = *(const s8v*)&qlo[qbase + s * 32 + lk * 8];
    }
    float vmax[4] = {NEG_INF, NEG_INF, NEG_INF, NEG_INF};
    float vsum[4] = {0.f, 0.f, 0.f, 0.f};
    for (int kc = 0; kc < L; kc += 128) {
        __syncthreads();
#pragma unroll
        for (int q = 0; q < 8; ++q) {
            const int arr = q >> 2;                    // compile-time per q
            const int rem = tid + ((q & 3) << 8);
            const int row = rem >> 3, part = rem & 7;
            const short* src = arr ? klo : khi;
            s8v v = *(const s8v*)&src[((size_t)bh * L + kc + row) * HD + part * 8];
            short* dst = arr ? Kl : Kh;
            *(s8v*)&dst[row * 72 + part * 8] = v;
        }
        __syncthreads();
#pragma unroll
        for (int kt = 0; kt < 8; ++kt) {
            int krow = kt * 16 + lr;
            s8v b0h = *(const s8v*)&Kh[krow * 72 + lk * 8];
            s8v b0l = *(const s8v*)&Kl[krow * 72 + lk * 8];
            s8v b1h = *(const s8v*)&Kh[krow * 72 + 32 + lk * 8];
            s8v b1l = *(const s8v*)&Kl[krow * 72 + 32 + lk * 8];
            f32x4 c = {0.f, 0.f, 0.f, 0.f};
            c = __builtin_amdgcn_mfma_f32_16x16x32_bf16(qf_h[0], b0h, c, 0, 0, 0);
            c = __builtin_amdgcn_mfma_f32_16x16x32_bf16(qf_h[0], b0l, c, 0, 0, 0);
            c = __builtin_amdgcn_mfma_f32_16x16x32_bf16(qf_l[0], b0h, c, 0, 0, 0);
            c = __builtin_amdgcn_mfma_f32_16x16x32_bf16(qf_h[1], b1h, c, 0, 0, 0);
            c = __builtin_amdgcn_mfma_f32_16x16x32_bf16(qf_h[1], b1l, c, 0, 0, 0);
            c = __builtin_amdgcn_mfma_f32_16x16x32_bf16(qf_l[1], b1h, c, 0, 0, 0);
#pragma unroll
            for (int r = 0; r < 4; ++r) {
                vmax[r] = fmaxf(vmax[r], c[r]);
                vsum[r] += c[r];
            }
        }
    }
#pragma unroll
    for (int off = 1; off < 16; off <<= 1)
#pragma unroll
        for (int r = 0; r < 4; ++r) {
            vmax[r] = fmaxf(vmax[r], __shfl_xor(vmax[r], off));
            vsum[r] += __shfl_xor(vsum[r], off);
        }
    if (lr == 0)
#pragma unroll
        for (int r = 0; r < 4; ++r)
            sp[(size_t)bh * L + q0 + w * 16 + lk * 4 + r] =
                SCALE * (vmax[r] - vsum[r] * (1.0f / (float)L));
}

// ---------------------------------------------------------------------------
// base[b,h,d] = mean_l vh[b,h,l,d]
// ---------------------------------------------------------------------------
__global__ __launch_bounds__(256) void base_kernel(const float* __restrict__ vh,
                                                   float* __restrict__ base)
{
    const int bh = blockIdx.x;
    const int tid = threadIdx.x;
    const int d = tid & 63, lg = tid >> 6;
    const float* V = vh + (size_t)bh * L * HD;
    float s = 0;
    for (int l = lg; l < L; l += 4) s += V[(size_t)l * HD + d];
    __shared__ float red[256];
    red[tid] = s;
    __syncthreads();
    if (tid < 64)
        base[bh * HD + d] = (red[d] + red[64 + d] + red[128 + d] + red[192 + d]) * (1.0f / (float)L);
}

// ---------------------------------------------------------------------------
// top-40 of sparsity per (b,h). Iterative argmax, shuffle-based (2 barriers/it).
// ---------------------------------------------------------------------------
__global__ __launch_bounds__(256) void topk_kernel(const float* __restrict__ sp,
                                                   int* __restrict__ topk)
{
    const int bh = blockIdx.x;
    const int tid = threadIdx.x;
    const int lane = tid & 63, w = tid >> 6;
    __shared__ float vals[L];
    __shared__ float wm[4];
    __shared__ int wi[4];
    for (int i = tid; i < L; i += 256) vals[i] = sp[(size_t)bh * L + i];
    __syncthreads();
    for (int it = 0; it < TOPU; ++it) {
        float bv = NEG_INF; int bi = L;
        for (int i = tid; i < L; i += 256) {
            float v = vals[i];
            if (v > bv) { bv = v; bi = i; }   // strided scan, keeps lowest idx on tie
        }
#pragma unroll
        for (int off = 1; off < 64; off <<= 1) {
            float ov = __shfl_xor(bv, off);
            int oi = __shfl_xor(bi, off);
            if (ov > bv || (ov == bv && oi < bi)) { bv = ov; bi = oi; }
        }
        if (lane == 0) { wm[w] = bv; wi[w] = bi; }
        __syncthreads();
        if (tid == 0) {
            float fb = wm[0]; int fi = wi[0];
#pragma unroll
            for (int k = 1; k < 4; ++k)
                if (wm[k] > fb || (wm[k] == fb && wi[k] < fi)) { fb = wm[k]; fi = wi[k]; }
            topk[bh * TOPU + it] = fi;
            vals[fi] = NEG_INF;
        }
        __syncthreads();
    }
}

// ---------------------------------------------------------------------------
// Flash attention partials for the 40 selected queries, keys split 8 ways.
// ---------------------------------------------------------------------------
__global__ __launch_bounds__(256) void attn_part_kernel(const float* __restrict__ qh,
    const float* __restrict__ kh, const float* __restrict__ vh,
    const int* __restrict__ topk,
    float* __restrict__ pm, float* __restrict__ pl, float* __restrict__ pacc)
{
    const int bh = blockIdx.x, chunk = blockIdx.y;
    const int tid = threadIdx.x;
    const int w = tid >> 6, lane = tid & 63;
    const float* Q = qh + (size_t)bh * L * HD;
    const float* K = kh + (size_t)bh * L * HD;
    const float* V = vh + (size_t)bh * L * HD;
    __shared__ int idx_s[TOPU];
    __shared__ float Qs[TOPU][HD];
    __shared__ float Ks[64][65];
    __shared__ float Vs[64][65];
    if (tid < TOPU) idx_s[tid] = topk[bh * TOPU + tid];
    __syncthreads();
    for (int e = tid; e < TOPU * HD; e += 256) {
        int u = e >> 6, d = e & 63;
        Qs[u][d] = Q[(size_t)idx_s[u] * HD + d];
    }
    float m[10], lsum[10], acc[10];
#pragma unroll
    for (int u = 0; u < 10; u++) { m[u] = NEG_INF; lsum[u] = 0.f; acc[u] = 0.f; }
    __syncthreads();
    const int kbase = chunk * (L / 8);
    for (int k0 = kbase; k0 < kbase + L / 8; k0 += 64) {
        for (int e = tid; e < 64 * HD; e += 256) {
            int r = e >> 6, c = e & 63;
            Ks[r][c] = K[(size_t)(k0 + r) * HD + c];
            Vs[r][c] = V[(size_t)(k0 + r) * HD + c];
        }
        __syncthreads();
#pragma unroll
        for (int u = 0; u < 10; u++) {
            const int qq = w * 10 + u;
            float s = 0;
#pragma unroll
            for (int d = 0; d < HD; d++) s += Qs[qq][d] * Ks[lane][d];
            s *= SCALE;
            float tmax = s;
#pragma unroll
            for (int off = 32; off >= 1; off >>= 1) tmax = fmaxf(tmax, __shfl_xor(tmax, off));
            float mnew = fmaxf(m[u], tmax);
            float alpha = __expf(m[u] - mnew);
            float p = __expf(s - mnew);
            float psum = p;
#pragma unroll
            for (int off = 32; off >= 1; off >>= 1) psum += __shfl_xor(psum, off);
            lsum[u] = lsum[u] * alpha + psum;
            float aa0 = 0.f, aa1 = 0.f, aa2 = 0.f, aa3 = 0.f;
            for (int k = 0; k < 64; k += 4) {
                aa0 += __shfl(p, k)     * Vs[k][lane];
                aa1 += __shfl(p, k + 1) * Vs[k + 1][lane];
                aa2 += __shfl(p, k + 2) * Vs[k + 2][lane];
                aa3 += __shfl(p, k + 3) * Vs[k + 3][lane];
            }
            acc[u] = acc[u] * alpha + (aa0 + aa1) + (aa2 + aa3);
            m[u] = mnew;
        }
        __syncthreads();
    }
#pragma unroll
    for (int u = 0; u < 10; u++) {
        int uu = w * 10 + u;
        size_t pidx = (size_t)(bh * 8 + chunk) * TOPU + uu;
        pacc[pidx * HD + lane] = acc[u];
        if (lane == 0) { pm[pidx] = m[u]; pl[pidx] = lsum[u]; }
    }
}

// ---------------------------------------------------------------------------
// Combine 8 chunk-partials -> dctx = softmax ctx - base.
// ---------------------------------------------------------------------------
__global__ __launch_bounds__(256) void attn_combine_kernel(const float* __restrict__ pm,
    const float* __restrict__ pl, const float* __restrict__ pacc,
    const float* __restrict__ base, float* __restrict__ dctx)
{
    const int bh = blockIdx.x;
    const int tid = threadIdx.x;
    const int w = tid >> 6, lane = tid & 63;
    for (int u = w * 10; u < w * 10 + 10; ++u) {
        float mstar = NEG_INF;
#pragma unroll
        for (int c = 0; c < 8; ++c)
            mstar = fmaxf(mstar, pm[(size_t)(bh * 8 + c) * TOPU + u]);
        float av = 0.f, lv = 0.f;
#pragma unroll
        for (int c = 0; c < 8; ++c) {
            size_t pidx = (size_t)(bh * 8 + c) * TOPU + u;
            float al = __expf(pm[pidx] - mstar);
            lv += al * pl[pidx];
            av += al * pacc[pidx * HD + lane];
        }
        dctx[((size_t)bh * TOPU + u) * HD + lane] = av / lv - base[bh * HD + lane];
    }
}

// ---------------------------------------------------------------------------
// base_out[b][j] = bo[j] + sum_d base_flat[b][d] * Wo[j][d]
// ---------------------------------------------------------------------------
__global__ __launch_bounds__(256) void base_out_kernel(const float* __restrict__ base,
    const float* __restrict__ Wo, const float* __restrict__ bo, float* __restrict__ bout)
{
    const int blk = blockIdx.x;
    const int b = blk >> 4;
    const int j0 = (blk & 15) * 64;
    const int tid = threadIdx.x;
    const int w = tid >> 6, lane = tid & 63;
    float bf[16];
#pragma unroll
    for (int t = 0; t < 16; t++) bf[t] = base[b * DM + lane + 64 * t];
    for (int jj = w; jj < 64; jj += 4) {
        int j = j0 + jj;
        float s = 0;
#pragma unroll
        for (int t = 0; t < 16; t++) s += bf[t] * Wo[(size_t)j * DM + lane + 64 * t];
#pragma unroll
        for (int off = 32; off >= 1; off >>= 1) s += __shfl_xor(s, off);
        if (lane == 0) bout[b * DM + j] = s + bo[j];
    }
}

// ---------------------------------------------------------------------------
// out[b,l,:] = base_out[b,:]  (broadcast fill, float4)
// ---------------------------------------------------------------------------
__global__ void fill_kernel(const float* __restrict__ bout, float* __restrict__ out)
{
    size_t i = (size_t)blockIdx.x * blockDim.x + threadIdx.x;
    const size_t total = (size_t)BATCH * L * DM / 4;
    if (i >= total) return;
    int j4 = (int)(i & (DM / 4 - 1));
    int b = (int)(i / ((size_t)L * DM / 4));
    ((float4*)out)[i] = ((const float4*)bout)[b * (DM / 4) + j4];
}

// ---------------------------------------------------------------------------
// Correction GEMM: out[b,l(r), jt*64+jj] += dctx[r,:] . Wo[j, h*64:(h+1)*64]
// grid (h*16 + jt), 256 threads. dctx rows in LDS (broadcast reads), Wo column
// per-thread in regs (each Wo element read exactly once grid-wide). Per-lane
// parallel atomics on 64 consecutive floats.
// ---------------------------------------------------------------------------
__global__ __launch_bounds__(256) void corr_kernel(const int* __restrict__ topk,
    const float* __restrict__ dctx, const float* __restrict__ Wo, float* __restrict__ out)
{
    const int h = blockIdx.x >> 4, jt = blockIdx.x & 15;
    const int tid = threadIdx.x;
    const int lane = tid & 63, w = tid >> 6;
    __shared__ float D[80][68];
    __shared__ int ls[80];
    for (int e = tid; e < 80 * 16; e += 256) {
        int r = e >> 4, qd = e & 15;
        int b = r / TOPU, u = r - b * TOPU;
        size_t g = (size_t)(b * NH + h) * TOPU + u;
        *(float4*)&D[r][qd * 4] = *(const float4*)&dctx[g * HD + qd * 4];
    }
    if (tid < 80) {
        int b = tid / TOPU, u = tid - b * TOPU;
        ls[tid] = topk[(b * NH + h) * TOPU + u];
    }
    const int j = jt * 64 + lane;
    float wreg[64];
    const float* wp = &Wo[(size_t)j * DM + h * HD];
#pragma unroll
    for (int d4 = 0; d4 < 16; ++d4) {
        float4 v = *(const float4*)&wp[d4 * 4];
        wreg[d4 * 4 + 0] = v.x; wreg[d4 * 4 + 1] = v.y;
        wreg[d4 * 4 + 2] = v.z; wreg[d4 * 4 + 3] = v.w;
    }
    __syncthreads();
#pragma unroll
    for (int rr = 0; rr < 20; ++rr) {
        int r = w * 20 + rr;
        float s = 0.f;
#pragma unroll
        for (int d4 = 0; d4 < 16; ++d4) {
            float4 dv = *(const float4*)&D[r][d4 * 4];
            s += dv.x * wreg[d4 * 4] + dv.y * wreg[d4 * 4 + 1] +
                 dv.z * wreg[d4 * 4 + 2] + dv.w * wreg[d4 * 4 + 3];
        }
        int b = r / TOPU;
        atomicAdd(&out[((size_t)b * L + ls[r]) * DM + j], s);
    }
}

extern "C" void kernel_launch(void* const* d_in, const int* in_sizes, int n_in,
                              void* d_out, int out_size, void* d_ws, size_t ws_size,
                              hipStream_t stream)
{
    const float* query = (const float*)d_in[0];
    const float* key   = (const float*)d_in[1];
    const float* value = (const float*)d_in[2];
    const float* Wq = (const float*)d_in[3];
    const float* bq = (const float*)d_in[4];
    const float* Wk = (const float*)d_in[5];
    const float* bk = (const float*)d_in[6];
    const float* Wv = (const float*)d_in[7];
    const float* bv = (const float*)d_in[8];
    const float* Wo = (const float*)d_in[9];
    const float* bo = (const float*)d_in[10];
    float* out = (float*)d_out;

    const size_t headsz = (size_t)BATCH * NH * L * HD;  // 4,194,304
    const size_t wsz    = (size_t)DM * DM;              // 1,048,576

    float* ws = (float*)d_ws;
    float* qh   = ws;
    float* kh   = qh + headsz;
    float* vh   = kh + headsz;
    float* sp   = vh + headsz;                       // 65536
    float* base = sp + (size_t)BATCH * NH * L;       // 2048
    float* dctx = base + BATCH * NH * HD;            // 81920
    float* bout = dctx + (size_t)BATCH * NH * TOPU * HD;
    int*   topk = (int*)(bout + BATCH * DM);         // 1280 ints
    float* pm   = (float*)(topk + 1280);             // 10240
    float* pl   = pm + (size_t)BATCH * NH * 8 * TOPU;
    float* pacc = pl + (size_t)BATCH * NH * 8 * TOPU;  // 655360
    short* qhi  = (short*)(pacc + (size_t)BATCH * NH * 8 * TOPU * HD);
    short* qlo  = qhi + headsz;
    short* khi  = qlo + headsz;
    short* klo  = khi + headsz;
    short* xin_hi = klo + headsz;                    // reused per projection
    short* xin_lo = xin_hi + headsz;
    short* w_hi   = xin_lo + headsz;                 // reused per projection
    short* w_lo   = w_hi + wsz;

    const int n4_in = (int)(headsz / 4);             // 1,048,576
    const int n4_w  = (int)(wsz / 4);                // 262,144
    dim3 gproj(8, 32);

    // Q projection
    split_kernel<<<(n4_w + 255) / 256, 256, 0, stream>>>((const float4*)Wq, w_hi, w_lo, n4_w);
    split_kernel<<<(n4_in + 255) / 256, 256, 0, stream>>>((const float4*)query, xin_hi, xin_lo, n4_in);
    proj_mfma_kernel<<<gproj, 256, 0, stream>>>(xin_hi, xin_lo, w_hi, w_lo, bq, qh, qhi, qlo);
    // K projection
    split_kernel<<<(n4_w + 255) / 256, 256, 0, stream>>>((const float4*)Wk, w_hi, w_lo, n4_w);
    split_kernel<<<(n4_in + 255) / 256, 256, 0, stream>>>((const float4*)key, xin_hi, xin_lo, n4_in);
    proj_mfma_kernel<<<gproj, 256, 0, stream>>>(xin_hi, xin_lo, w_hi, w_lo, bk, kh, khi, klo);
    // V projection (no split output needed)
    split_kernel<<<(n4_w + 255) / 256, 256, 0, stream>>>((const float4*)Wv, w_hi, w_lo, n4_w);
    split_kernel<<<(n4_in + 255) / 256, 256, 0, stream>>>((const float4*)value, xin_hi, xin_lo, n4_in);
    proj_mfma_kernel<<<gproj, 256, 0, stream>>>(xin_hi, xin_lo, w_hi, w_lo, bv, vh, (short*)0, (short*)0);

    sparsity_mfma_kernel<<<dim3(BATCH * NH, L / 64), 256, 0, stream>>>(qhi, qlo, khi, klo, sp);
    base_kernel<<<BATCH * NH, 256, 0, stream>>>(vh, base);
    topk_kernel<<<BATCH * NH, 256, 0, stream>>>(sp, topk);
    attn_part_kernel<<<dim3(BATCH * NH, 8), 256, 0, stream>>>(qh, kh, vh, topk, pm, pl, pacc);
    attn_combine_kernel<<<BATCH * NH, 256, 0, stream>>>(pm, pl, pacc, base, dctx);
    base_out_kernel<<<BATCH * 16, 256, 0, stream>>>(base, Wo, bo, bout);
    fill_kernel<<<(int)(((size_t)BATCH * L * DM / 4 + 255) / 256), 256, 0, stream>>>(bout, out);
    corr_kernel<<<NH * 16, 256, 0, stream>>>(topk, dctx, Wo, out);
}

// Round 5
// 521.047 us; speedup vs baseline: 3.3989x; 1.2160x over previous
//
#include <hip/hip_runtime.h>
#include <math.h>

#define L 2048
#define DM 1024
#define HD 64
#define NH 16
#define BATCH 2
#define TOPU 40
#define SCALE 0.125f
#define NEG_INF (-1e30f)

typedef short s8v __attribute__((ext_vector_type(8)));
typedef short s4v __attribute__((ext_vector_type(4)));
typedef float f32x4 __attribute__((ext_vector_type(4)));

// bf16 round-to-nearest-even split helpers (bit-level, avoids type issues)
__device__ inline short f2bf(float x) {
    union { float f; unsigned u; } v; v.f = x;
    unsigned r = v.u + 0x7FFFu + ((v.u >> 16) & 1u);
    return (short)(r >> 16);
}
__device__ inline float bf2f(short b) {
    union { unsigned u; float f; } v; v.u = ((unsigned)(unsigned short)b) << 16;
    return v.f;
}

// ---------------------------------------------------------------------------
// Split fp32 -> bf16 hi + bf16 lo (Markidis split). float4-vectorized.
// ---------------------------------------------------------------------------
__global__ __launch_bounds__(256) void split_kernel(const float4* __restrict__ in,
    short* __restrict__ hi, short* __restrict__ lo, int n4)
{
    int i = blockIdx.x * 256 + threadIdx.x;
    if (i >= n4) return;
    float4 x = in[i];
    float xs[4] = {x.x, x.y, x.z, x.w};
    s4v h, l;
#pragma unroll
    for (int j = 0; j < 4; ++j) {
        short hh = f2bf(xs[j]);
        h[j] = hh;
        l[j] = f2bf(xs[j] - bf2f(hh));
    }
    *(s4v*)&hi[(size_t)i * 4] = h;
    *(s4v*)&lo[(size_t)i * 4] = l;
}

// ---------------------------------------------------------------------------
// Split-bf16 MFMA projection GEMM (NT): Y = X @ W^T + bias.
// X[4096][1024], W[1024][1024] as hi/lo bf16. 128x128 tile, BK=32, 4 waves,
// each wave 64x64 (4x4 frags of 16x16x32). LDS rows padded 32->40 shorts.
// ---------------------------------------------------------------------------
__global__ __launch_bounds__(256) void proj_mfma_kernel(
    const short* __restrict__ Xhi, const short* __restrict__ Xlo,
    const short* __restrict__ Whi, const short* __restrict__ Wlo,
    const float* __restrict__ bias, float* __restrict__ Y,
    short* __restrict__ Yhi, short* __restrict__ Ylo)
{
    __shared__ short Ah[128 * 40], Al[128 * 40], Bh[128 * 40], Bl[128 * 40];
    const int i0 = blockIdx.y * 128, j0 = blockIdx.x * 128;
    const int tid = threadIdx.x;
    const int wid = tid >> 6, lane = tid & 63;
    const int wm = wid >> 1, wn = wid & 1;
    const int lr = lane & 15, lk = lane >> 4;
    f32x4 acc[4][4];
    f32x4 zero = {0.f, 0.f, 0.f, 0.f};
#pragma unroll
    for (int m = 0; m < 4; ++m)
#pragma unroll
        for (int n = 0; n < 4; ++n) acc[m][n] = zero;

    for (int k0 = 0; k0 < DM; k0 += 32) {
        __syncthreads();
#pragma unroll
        for (int q = 0; q < 8; ++q) {
            const int arr = q >> 1;                    // compile-time per q
            const int rem = tid + ((q & 1) << 8);
            const int row = rem >> 2, part = rem & 3;
            const short* src = (arr == 0) ? Xhi : (arr == 1) ? Xlo : (arr == 2) ? Whi : Wlo;
            const int gr = ((arr < 2) ? i0 : j0) + row;
            s8v v = *(const s8v*)&src[(size_t)gr * DM + k0 + part * 8];
            short* dst = (arr == 0) ? Ah : (arr == 1) ? Al : (arr == 2) ? Bh : Bl;
            *(s8v*)&dst[row * 40 + part * 8] = v;
        }
        __syncthreads();
        s8v af_h[4], af_l[4];
#pragma unroll
        for (int m = 0; m < 4; ++m) {
            int r = wm * 64 + m * 16 + lr;
            af_h[m] = *(const s8v*)&Ah[r * 40 + lk * 8];
            af_l[m] = *(const s8v*)&Al[r * 40 + lk * 8];
        }
#pragma unroll
        for (int n = 0; n < 4; ++n) {
            int r = wn * 64 + n * 16 + lr;
            s8v bf_h = *(const s8v*)&Bh[r * 40 + lk * 8];
            s8v bf_l = *(const s8v*)&Bl[r * 40 + lk * 8];
#pragma unroll
            for (int m = 0; m < 4; ++m) {
                acc[m][n] = __builtin_amdgcn_mfma_f32_16x16x32_bf16(af_h[m], bf_h, acc[m][n], 0, 0, 0);
                acc[m][n] = __builtin_amdgcn_mfma_f32_16x16x32_bf16(af_h[m], bf_l, acc[m][n], 0, 0, 0);
                acc[m][n] = __builtin_amdgcn_mfma_f32_16x16x32_bf16(af_l[m], bf_h, acc[m][n], 0, 0, 0);
            }
        }
    }
    // C/D layout: col = lane&15 (N), row = (lane>>4)*4 + reg (M)  [m89/m91]
#pragma unroll
    for (int m = 0; m < 4; ++m)
#pragma unroll
        for (int n = 0; n < 4; ++n)
#pragma unroll
            for (int rg = 0; rg < 4; ++rg) {
                int i = i0 + wm * 64 + m * 16 + lk * 4 + rg;
                int j = j0 + wn * 64 + n * 16 + lr;
                float val = acc[m][n][rg] + bias[j];
                int b = i >> 11, l = i & (L - 1);
                int h = j >> 6, dd = j & 63;
                size_t idx = (((size_t)(b * NH + h)) * L + l) * HD + dd;
                Y[idx] = val;
                if (Yhi) {
                    short hh = f2bf(val);
                    Yhi[idx] = hh;
                    Ylo[idx] = f2bf(val - bf2f(hh));
                }
            }
}

// ---------------------------------------------------------------------------
// Sparsity via split-bf16 MFMA: per (bh, 64-query tile) compute
// scale*(max_k S - sum_k S / L) over all 2048 keys.
// ---------------------------------------------------------------------------
__global__ __launch_bounds__(256) void sparsity_mfma_kernel(
    const short* __restrict__ qhi, const short* __restrict__ qlo,
    const short* __restrict__ khi, const short* __restrict__ klo,
    float* __restrict__ sp)
{
    __shared__ short Kh[128 * 72], Kl[128 * 72];
    const int bh = blockIdx.x, q0 = blockIdx.y * 64;
    const int tid = threadIdx.x;
    const int w = tid >> 6, lane = tid & 63;
    const int lr = lane & 15, lk = lane >> 4;
    const size_t qbase = ((size_t)bh * L + q0 + w * 16 + lr) * HD;
    s8v qf_h[2], qf_l[2];
#pragma unroll
    for (int s = 0; s < 2; ++s) {
        qf_h[s] = *(const s8v*)&qhi[qbase + s * 32 + lk * 8];
        qf_l[s] = *(const s8v*)&qlo[qbase + s * 32 + lk * 8];
    }
    float vmax[4] = {NEG_INF, NEG_INF, NEG_INF, NEG_INF};
    float vsum[4] = {0.f, 0.f, 0.f, 0.f};
    for (int kc = 0; kc < L; kc += 128) {
        __syncthreads();
#pragma unroll
        for (int q = 0; q < 8; ++q) {
            const int arr = q >> 2;                    // compile-time per q
            const int rem = tid + ((q & 3) << 8);
            const int row = rem >> 3, part = rem & 7;
            const short* src = arr ? klo : khi;
            s8v v = *(const s8v*)&src[((size_t)bh * L + kc + row) * HD + part * 8];
            short* dst = arr ? Kl : Kh;
            *(s8v*)&dst[row * 72 + part * 8] = v;
        }
        __syncthreads();
#pragma unroll
        for (int kt = 0; kt < 8; ++kt) {
            int krow = kt * 16 + lr;
            s8v b0h = *(const s8v*)&Kh[krow * 72 + lk * 8];
            s8v b0l = *(const s8v*)&Kl[krow * 72 + lk * 8];
            s8v b1h = *(const s8v*)&Kh[krow * 72 + 32 + lk * 8];
            s8v b1l = *(const s8v*)&Kl[krow * 72 + 32 + lk * 8];
            f32x4 c = {0.f, 0.f, 0.f, 0.f};
            c = __builtin_amdgcn_mfma_f32_16x16x32_bf16(qf_h[0], b0h, c, 0, 0, 0);
            c = __builtin_amdgcn_mfma_f32_16x16x32_bf16(qf_h[0], b0l, c, 0, 0, 0);
            c = __builtin_amdgcn_mfma_f32_16x16x32_bf16(qf_l[0], b0h, c, 0, 0, 0);
            c = __builtin_amdgcn_mfma_f32_16x16x32_bf16(qf_h[1], b1h, c, 0, 0, 0);
            c = __builtin_amdgcn_mfma_f32_16x16x32_bf16(qf_h[1], b1l, c, 0, 0, 0);
            c = __builtin_amdgcn_mfma_f32_16x16x32_bf16(qf_l[1], b1h, c, 0, 0, 0);
#pragma unroll
            for (int r = 0; r < 4; ++r) {
                vmax[r] = fmaxf(vmax[r], c[r]);
                vsum[r] += c[r];
            }
        }
    }
#pragma unroll
    for (int off = 1; off < 16; off <<= 1)
#pragma unroll
        for (int r = 0; r < 4; ++r) {
            vmax[r] = fmaxf(vmax[r], __shfl_xor(vmax[r], off));
            vsum[r] += __shfl_xor(vsum[r], off);
        }
    if (lr == 0)
#pragma unroll
        for (int r = 0; r < 4; ++r)
            sp[(size_t)bh * L + q0 + w * 16 + lk * 4 + r] =
                SCALE * (vmax[r] - vsum[r] * (1.0f / (float)L));
}

// ---------------------------------------------------------------------------
// base partial: pbase[bh][chunk][d] = sum over 128 rows of vh. grid (32,16).
// float4 loads, 16 row-groups x 16 d4-columns per block.
// ---------------------------------------------------------------------------
__global__ __launch_bounds__(256) void base_part_kernel(const float* __restrict__ vh,
                                                        float* __restrict__ pbase)
{
    const int bh = blockIdx.x, chunk = blockIdx.y;
    const int tid = threadIdx.x;
    const int d4 = tid & 15, rg = tid >> 4;
    const float* V = vh + ((size_t)bh * L + chunk * 128) * HD;
    f32x4 s = {0.f, 0.f, 0.f, 0.f};
    for (int r = rg; r < 128; r += 16)
        s += *(const f32x4*)&V[(size_t)r * HD + d4 * 4];
    __shared__ f32x4 red[256];
    red[tid] = s;
    __syncthreads();
    if (tid < 16) {
        f32x4 t = red[tid];
#pragma unroll
        for (int g = 1; g < 16; ++g) t += red[g * 16 + tid];
        *(f32x4*)&pbase[((size_t)bh * 16 + chunk) * HD + tid * 4] = t;
    }
}

// base[bh][d] = (sum over 16 chunk partials) / L
__global__ __launch_bounds__(64) void base_combine_kernel(const float* __restrict__ pbase,
                                                          float* __restrict__ base)
{
    const int bh = blockIdx.x;
    const int d = threadIdx.x;
    float s = 0.f;
#pragma unroll
    for (int c = 0; c < 16; ++c) s += pbase[((size_t)bh * 16 + c) * HD + d];
    base[bh * HD + d] = s * (1.0f / (float)L);
}

// ---------------------------------------------------------------------------
// top-40 of sparsity per (b,h). Iterative argmax, shuffle-based (2 barriers/it).
// ---------------------------------------------------------------------------
__global__ __launch_bounds__(256) void topk_kernel(const float* __restrict__ sp,
                                                   int* __restrict__ topk)
{
    const int bh = blockIdx.x;
    const int tid = threadIdx.x;
    const int lane = tid & 63, w = tid >> 6;
    __shared__ float vals[L];
    __shared__ float wm[4];
    __shared__ int wi[4];
    for (int i = tid; i < L; i += 256) vals[i] = sp[(size_t)bh * L + i];
    __syncthreads();
    for (int it = 0; it < TOPU; ++it) {
        float bv = NEG_INF; int bi = L;
        for (int i = tid; i < L; i += 256) {
            float v = vals[i];
            if (v > bv) { bv = v; bi = i; }   // strided scan, keeps lowest idx on tie
        }
#pragma unroll
        for (int off = 1; off < 64; off <<= 1) {
            float ov = __shfl_xor(bv, off);
            int oi = __shfl_xor(bi, off);
            if (ov > bv || (ov == bv && oi < bi)) { bv = ov; bi = oi; }
        }
        if (lane == 0) { wm[w] = bv; wi[w] = bi; }
        __syncthreads();
        if (tid == 0) {
            float fb = wm[0]; int fi = wi[0];
#pragma unroll
            for (int k = 1; k < 4; ++k)
                if (wm[k] > fb || (wm[k] == fb && wi[k] < fi)) { fb = wm[k]; fi = wi[k]; }
            topk[bh * TOPU + it] = fi;
            vals[fi] = NEG_INF;
        }
        __syncthreads();
    }
}

// ---------------------------------------------------------------------------
// Flash attention partials for the 40 selected queries, keys split 8 ways.
// ---------------------------------------------------------------------------
__global__ __launch_bounds__(256) void attn_part_kernel(const float* __restrict__ qh,
    const float* __restrict__ kh, const float* __restrict__ vh,
    const int* __restrict__ topk,
    float* __restrict__ pm, float* __restrict__ pl, float* __restrict__ pacc)
{
    const int bh = blockIdx.x, chunk = blockIdx.y;
    const int tid = threadIdx.x;
    const int w = tid >> 6, lane = tid & 63;
    const float* Q = qh + (size_t)bh * L * HD;
    const float* K = kh + (size_t)bh * L * HD;
    const float* V = vh + (size_t)bh * L * HD;
    __shared__ int idx_s[TOPU];
    __shared__ float Qs[TOPU][HD];
    __shared__ float Ks[64][65];
    __shared__ float Vs[64][65];
    if (tid < TOPU) idx_s[tid] = topk[bh * TOPU + tid];
    __syncthreads();
    for (int e = tid; e < TOPU * HD; e += 256) {
        int u = e >> 6, d = e & 63;
        Qs[u][d] = Q[(size_t)idx_s[u] * HD + d];
    }
    float m[10], lsum[10], acc[10];
#pragma unroll
    for (int u = 0; u < 10; u++) { m[u] = NEG_INF; lsum[u] = 0.f; acc[u] = 0.f; }
    __syncthreads();
    const int kbase = chunk * (L / 8);
    for (int k0 = kbase; k0 < kbase + L / 8; k0 += 64) {
        for (int e = tid; e < 64 * HD; e += 256) {
            int r = e >> 6, c = e & 63;
            Ks[r][c] = K[(size_t)(k0 + r) * HD + c];
            Vs[r][c] = V[(size_t)(k0 + r) * HD + c];
        }
        __syncthreads();
#pragma unroll
        for (int u = 0; u < 10; u++) {
            const int qq = w * 10 + u;
            float s = 0;
#pragma unroll
            for (int d = 0; d < HD; d++) s += Qs[qq][d] * Ks[lane][d];
            s *= SCALE;
            float tmax = s;
#pragma unroll
            for (int off = 32; off >= 1; off >>= 1) tmax = fmaxf(tmax, __shfl_xor(tmax, off));
            float mnew = fmaxf(m[u], tmax);
            float alpha = __expf(m[u] - mnew);
            float p = __expf(s - mnew);
            float psum = p;
#pragma unroll
            for (int off = 32; off >= 1; off >>= 1) psum += __shfl_xor(psum, off);
            lsum[u] = lsum[u] * alpha + psum;
            float aa0 = 0.f, aa1 = 0.f, aa2 = 0.f, aa3 = 0.f;
            for (int k = 0; k < 64; k += 4) {
                aa0 += __shfl(p, k)     * Vs[k][lane];
                aa1 += __shfl(p, k + 1) * Vs[k + 1][lane];
                aa2 += __shfl(p, k + 2) * Vs[k + 2][lane];
                aa3 += __shfl(p, k + 3) * Vs[k + 3][lane];
            }
            acc[u] = acc[u] * alpha + (aa0 + aa1) + (aa2 + aa3);
            m[u] = mnew;
        }
        __syncthreads();
    }
#pragma unroll
    for (int u = 0; u < 10; u++) {
        int uu = w * 10 + u;
        size_t pidx = (size_t)(bh * 8 + chunk) * TOPU + uu;
        pacc[pidx * HD + lane] = acc[u];
        if (lane == 0) { pm[pidx] = m[u]; pl[pidx] = lsum[u]; }
    }
}

// ---------------------------------------------------------------------------
// Combine 8 chunk-partials -> dctx = softmax ctx - base.
// ---------------------------------------------------------------------------
__global__ __launch_bounds__(256) void attn_combine_kernel(const float* __restrict__ pm,
    const float* __restrict__ pl, const float* __restrict__ pacc,
    const float* __restrict__ base, float* __restrict__ dctx)
{
    const int bh = blockIdx.x;
    const int tid = threadIdx.x;
    const int w = tid >> 6, lane = tid & 63;
    for (int u = w * 10; u < w * 10 + 10; ++u) {
        float mstar = NEG_INF;
#pragma unroll
        for (int c = 0; c < 8; ++c)
            mstar = fmaxf(mstar, pm[(size_t)(bh * 8 + c) * TOPU + u]);
        float av = 0.f, lv = 0.f;
#pragma unroll
        for (int c = 0; c < 8; ++c) {
            size_t pidx = (size_t)(bh * 8 + c) * TOPU + u;
            float al = __expf(pm[pidx] - mstar);
            lv += al * pl[pidx];
            av += al * pacc[pidx * HD + lane];
        }
        dctx[((size_t)bh * TOPU + u) * HD + lane] = av / lv - base[bh * HD + lane];
    }
}

// ---------------------------------------------------------------------------
// base_out[b][j] = bo[j] + sum_d base_flat[b][d] * Wo[j][d]
// ---------------------------------------------------------------------------
__global__ __launch_bounds__(256) void base_out_kernel(const float* __restrict__ base,
    const float* __restrict__ Wo, const float* __restrict__ bo, float* __restrict__ bout)
{
    const int blk = blockIdx.x;
    const int b = blk >> 4;
    const int j0 = (blk & 15) * 64;
    const int tid = threadIdx.x;
    const int w = tid >> 6, lane = tid & 63;
    float bf[16];
#pragma unroll
    for (int t = 0; t < 16; t++) bf[t] = base[b * DM + lane + 64 * t];
    for (int jj = w; jj < 64; jj += 4) {
        int j = j0 + jj;
        float s = 0;
#pragma unroll
        for (int t = 0; t < 16; t++) s += bf[t] * Wo[(size_t)j * DM + lane + 64 * t];
#pragma unroll
        for (int off = 32; off >= 1; off >>= 1) s += __shfl_xor(s, off);
        if (lane == 0) bout[b * DM + j] = s + bo[j];
    }
}

// ---------------------------------------------------------------------------
// out[b,l,:] = base_out[b,:]  (broadcast fill, float4)
// ---------------------------------------------------------------------------
__global__ void fill_kernel(const float* __restrict__ bout, float* __restrict__ out)
{
    size_t i = (size_t)blockIdx.x * blockDim.x + threadIdx.x;
    const size_t total = (size_t)BATCH * L * DM / 4;
    if (i >= total) return;
    int j4 = (int)(i & (DM / 4 - 1));
    int b = (int)(i / ((size_t)L * DM / 4));
    ((float4*)out)[i] = ((const float4*)bout)[b * (DM / 4) + j4];
}

// ---------------------------------------------------------------------------
// Correction GEMM: out[b,l(r), jt*64+jj] += dctx[r,:] . Wo[j, h*64:(h+1)*64]
// ---------------------------------------------------------------------------
__global__ __launch_bounds__(256) void corr_kernel(const int* __restrict__ topk,
    const float* __restrict__ dctx, const float* __restrict__ Wo, float* __restrict__ out)
{
    const int h = blockIdx.x >> 4, jt = blockIdx.x & 15;
    const int tid = threadIdx.x;
    const int lane = tid & 63, w = tid >> 6;
    __shared__ float D[80][68];
    __shared__ int ls[80];
    for (int e = tid; e < 80 * 16; e += 256) {
        int r = e >> 4, qd = e & 15;
        int b = r / TOPU, u = r - b * TOPU;
        size_t g = (size_t)(b * NH + h) * TOPU + u;
        *(float4*)&D[r][qd * 4] = *(const float4*)&dctx[g * HD + qd * 4];
    }
    if (tid < 80) {
        int b = tid / TOPU, u = tid - b * TOPU;
        ls[tid] = topk[(b * NH + h) * TOPU + u];
    }
    const int j = jt * 64 + lane;
    float wreg[64];
    const float* wp = &Wo[(size_t)j * DM + h * HD];
#pragma unroll
    for (int d4 = 0; d4 < 16; ++d4) {
        float4 v = *(const float4*)&wp[d4 * 4];
        wreg[d4 * 4 + 0] = v.x; wreg[d4 * 4 + 1] = v.y;
        wreg[d4 * 4 + 2] = v.z; wreg[d4 * 4 + 3] = v.w;
    }
    __syncthreads();
#pragma unroll
    for (int rr = 0; rr < 20; ++rr) {
        int r = w * 20 + rr;
        float s = 0.f;
#pragma unroll
        for (int d4 = 0; d4 < 16; ++d4) {
            float4 dv = *(const float4*)&D[r][d4 * 4];
            s += dv.x * wreg[d4 * 4] + dv.y * wreg[d4 * 4 + 1] +
                 dv.z * wreg[d4 * 4 + 2] + dv.w * wreg[d4 * 4 + 3];
        }
        int b = r / TOPU;
        atomicAdd(&out[((size_t)b * L + ls[r]) * DM + j], s);
    }
}

extern "C" void kernel_launch(void* const* d_in, const int* in_sizes, int n_in,
                              void* d_out, int out_size, void* d_ws, size_t ws_size,
                              hipStream_t stream)
{
    const float* query = (const float*)d_in[0];
    const float* key   = (const float*)d_in[1];
    const float* value = (const float*)d_in[2];
    const float* Wq = (const float*)d_in[3];
    const float* bq = (const float*)d_in[4];
    const float* Wk = (const float*)d_in[5];
    const float* bk = (const float*)d_in[6];
    const float* Wv = (const float*)d_in[7];
    const float* bv = (const float*)d_in[8];
    const float* Wo = (const float*)d_in[9];
    const float* bo = (const float*)d_in[10];
    float* out = (float*)d_out;

    const size_t headsz = (size_t)BATCH * NH * L * HD;  // 4,194,304
    const size_t wsz    = (size_t)DM * DM;              // 1,048,576

    float* ws = (float*)d_ws;
    float* qh   = ws;
    float* kh   = qh + headsz;
    float* vh   = kh + headsz;
    float* sp   = vh + headsz;                       // 65536
    float* base = sp + (size_t)BATCH * NH * L;       // 2048
    float* dctx = base + BATCH * NH * HD;            // 81920
    float* bout = dctx + (size_t)BATCH * NH * TOPU * HD;
    int*   topk = (int*)(bout + BATCH * DM);         // 1280 ints
    float* pm   = (float*)(topk + 1280);             // 10240
    float* pl   = pm + (size_t)BATCH * NH * 8 * TOPU;
    float* pacc = pl + (size_t)BATCH * NH * 8 * TOPU;  // 655360
    float* pbase = pacc + (size_t)BATCH * NH * 8 * TOPU * HD;  // 32*16*64 = 32768
    short* qhi  = (short*)(pbase + (size_t)BATCH * NH * 16 * HD);
    short* qlo  = qhi + headsz;
    short* khi  = qlo + headsz;
    short* klo  = khi + headsz;
    short* xin_hi = klo + headsz;                    // reused per projection
    short* xin_lo = xin_hi + headsz;
    short* w_hi   = xin_lo + headsz;                 // reused per projection
    short* w_lo   = w_hi + wsz;

    const int n4_in = (int)(headsz / 4);             // 1,048,576
    const int n4_w  = (int)(wsz / 4);                // 262,144
    dim3 gproj(8, 32);

    // Q projection
    split_kernel<<<(n4_w + 255) / 256, 256, 0, stream>>>((const float4*)Wq, w_hi, w_lo, n4_w);
    split_kernel<<<(n4_in + 255) / 256, 256, 0, stream>>>((const float4*)query, xin_hi, xin_lo, n4_in);
    proj_mfma_kernel<<<gproj, 256, 0, stream>>>(xin_hi, xin_lo, w_hi, w_lo, bq, qh, qhi, qlo);
    // K projection
    split_kernel<<<(n4_w + 255) / 256, 256, 0, stream>>>((const float4*)Wk, w_hi, w_lo, n4_w);
    split_kernel<<<(n4_in + 255) / 256, 256, 0, stream>>>((const float4*)key, xin_hi, xin_lo, n4_in);
    proj_mfma_kernel<<<gproj, 256, 0, stream>>>(xin_hi, xin_lo, w_hi, w_lo, bk, kh, khi, klo);
    // V projection (no split output needed)
    split_kernel<<<(n4_w + 255) / 256, 256, 0, stream>>>((const float4*)Wv, w_hi, w_lo, n4_w);
    split_kernel<<<(n4_in + 255) / 256, 256, 0, stream>>>((const float4*)value, xin_hi, xin_lo, n4_in);
    proj_mfma_kernel<<<gproj, 256, 0, stream>>>(xin_hi, xin_lo, w_hi, w_lo, bv, vh, (short*)0, (short*)0);

    sparsity_mfma_kernel<<<dim3(BATCH * NH, L / 64), 256, 0, stream>>>(qhi, qlo, khi, klo, sp);
    base_part_kernel<<<dim3(BATCH * NH, 16), 256, 0, stream>>>(vh, pbase);
    base_combine_kernel<<<BATCH * NH, 64, 0, stream>>>(pbase, base);
    topk_kernel<<<BATCH * NH, 256, 0, stream>>>(sp, topk);
    attn_part_kernel<<<dim3(BATCH * NH, 8), 256, 0, stream>>>(qh, kh, vh, topk, pm, pl, pacc);
    attn_combine_kernel<<<BATCH * NH, 256, 0, stream>>>(pm, pl, pacc, base, dctx);
    base_out_kernel<<<BATCH * 16, 256, 0, stream>>>(base, Wo, bo, bout);
    fill_kernel<<<(int)(((size_t)BATCH * L * DM / 4 + 255) / 256), 256, 0, stream>>>(bout, out);
    corr_kernel<<<NH * 16, 256, 0, stream>>>(topk, dctx, Wo, out);
}